// Round 7
// baseline (301.922 us; speedup 1.0000x reference)
//
#include <hip/hip_runtime.h>
#include <hip/hip_bf16.h>
#include <math.h>

#define B_SZ 256
#define F_SZ 2048
#define C_SZ 16384
#define P_SZ 8
#define N_SZ 32
#define NTILE 256   // C_SZ / BN softmax partials per row

typedef __bf16 bf16x8 __attribute__((ext_vector_type(8)));
typedef float f32x4 __attribute__((ext_vector_type(4)));
typedef unsigned short us8 __attribute__((ext_vector_type(8)));

typedef __attribute__((address_space(3))) unsigned int lds_u32;
typedef __attribute__((address_space(1))) const unsigned int glb_u32;

// s_waitcnt immediates (gfx9 encoding): vm[3:0] bits0-3, vm[5:4] bits15:14;
// exp bits4-6; lgkm bits8-11. Unused counters set to max.
#define WAITCNT_VM8   0x0F78   // vmcnt(8)
#define WAITCNT_VM0   0x0F70   // vmcnt(0)
#define WAITCNT_LGKM0 0xC07F   // lgkmcnt(0)

__device__ __forceinline__ unsigned short f2bf(float x) {
    union { float f; unsigned int u; } v; v.f = x;
    unsigned int r = v.u + 0x7FFFu + ((v.u >> 16) & 1u);  // RTN-even
    return (unsigned short)(r >> 16);
}

// pack bf16(x) into low16, bf16(y) into high16 (round-half-up) via v_perm
__device__ __forceinline__ unsigned int pk2bf(float x, float y) {
    union { float f; unsigned int u; } a, b; a.f = x; b.f = y;
    return __builtin_amdgcn_perm(b.u + 0x8000u, a.u + 0x8000u, 0x07060302u);
}

// ---------------- kernel 1: row norms + bf16 cast of inputs ----------------
__global__ __launch_bounds__(256) void prep_kernel(const float* __restrict__ inputs,
                                                   unsigned short* __restrict__ Abf,
                                                   float* __restrict__ norms) {
    const int row = blockIdx.x;
    const int tid = threadIdx.x;
    const float* rp = inputs + (size_t)row * F_SZ + tid * 8;
    float4 v0 = *(const float4*)(rp);
    float4 v1 = *(const float4*)(rp + 4);
    us8 o;
    o[0]=f2bf(v0.x); o[1]=f2bf(v0.y); o[2]=f2bf(v0.z); o[3]=f2bf(v0.w);
    o[4]=f2bf(v1.x); o[5]=f2bf(v1.y); o[6]=f2bf(v1.z); o[7]=f2bf(v1.w);
    *(us8*)(Abf + (size_t)row * F_SZ + tid * 8) = o;
    float ss = v0.x*v0.x + v0.y*v0.y + v0.z*v0.z + v0.w*v0.w
             + v1.x*v1.x + v1.y*v1.y + v1.z*v1.z + v1.w*v1.w;
    __shared__ float red[256];
    red[tid] = ss; __syncthreads();
    for (int s = 128; s > 0; s >>= 1) { if (tid < s) red[tid] += red[tid+s]; __syncthreads(); }
    if (tid == 0) norms[row] = sqrtf(red[0]);
}

// ---------------- kernel 2: outputs = inputs @ V^T ----------------
// BM=128, BN=64, BK=64, 256 thr. Pipelined: A = 3-deep LDS ring (glds, issued
// 2 ahead); B = fp32->VGPR (2 reg sets, loaded 2 ahead) ->bf16-> LDS dbuf
// (written 1 ahead). Raw s_barrier + vmcnt(8): newest 8 loads stay in flight.
#define BM 128
#define BN 64
#define BK 64
#define BPAD 72
#define KITERS (F_SZ / BK)   // 32

__global__ __launch_bounds__(256, 2) void gemm_kernel(const unsigned short* __restrict__ Abf,
                                                      const float* __restrict__ V,
                                                      float* __restrict__ Cout,
                                                      float* __restrict__ pmax,
                                                      float* __restrict__ psum) {
    __shared__ unsigned short As[3][BM * BK];    // 3 x 16 KB ring, swizzled
    __shared__ unsigned short Bs[2][BN * BPAD];  // 2 x 9 KB, padded
    __shared__ float sm[BM * 2], ss2[BM * 2];

    const int tid = threadIdx.x;
    const int lane = tid & 63;
    const int wid = tid >> 6;
    const int wm = wid >> 1, wn = wid & 1;       // 2 m-waves x 2 n-waves
    const int q = lane >> 4, l16 = lane & 15;

    // same-slab m-pair 8 ids apart -> same XCD L2 for V reuse
    const int bid = blockIdx.x;
    const int mhalf = (bid >> 3) & 1;
    const int slab  = (bid & 7) | ((bid >> 4) << 3);
    const int bm0 = mhalf * BM;
    const int bn0 = slab * BN;

    f32x4 acc[4][2];
    #pragma unroll
    for (int i = 0; i < 4; i++)
        #pragma unroll
        for (int j = 0; j < 2; j++) acc[i][j] = (f32x4){0.f, 0.f, 0.f, 0.f};

    // A staging map: row = j*32 + (tid>>3); stored chunk c = tid&7 holds kc = c^(row&7)
    const int arow = tid >> 3;
    const int akc = (tid & 7) ^ (arow & 7);
    const unsigned short* AgBase = Abf + (size_t)(bm0 + arow) * F_SZ + akc * 8;

    // B staging: col = tid>>2, seg = tid&3 (16 fp32)
    const int bcol = tid >> 2, bseg = tid & 3;
    const float* BgBase = V + (size_t)(bn0 + bcol) * F_SZ + bseg * 16;
    const int bsoff = bcol * BPAD + bseg * 16;

    float4 a0, a1, a2, a3;   // B reg set 0 (parity 0)
    float4 c0, c1, c2, c3;   // B reg set 1 (parity 1)

    auto issueA = [&](int ring, int k0) {
        #pragma unroll
        for (int j = 0; j < 4; ++j) {
            __builtin_amdgcn_global_load_lds(
                (glb_u32*)(AgBase + (size_t)j * 32 * F_SZ + k0),
                (lds_u32*)&As[ring][(j * 256 + wid * 64) * 8],
                16, 0, 0);
        }
    };
    auto loadB0 = [&](int k0) {
        a0 = *(const float4*)(BgBase + k0);     a1 = *(const float4*)(BgBase + k0 + 4);
        a2 = *(const float4*)(BgBase + k0 + 8); a3 = *(const float4*)(BgBase + k0 + 12);
    };
    auto loadB1 = [&](int k0) {
        c0 = *(const float4*)(BgBase + k0);     c1 = *(const float4*)(BgBase + k0 + 4);
        c2 = *(const float4*)(BgBase + k0 + 8); c3 = *(const float4*)(BgBase + k0 + 12);
    };
    auto writeB = [&](int buf, int set) {
        float4 x0 = set ? c0 : a0, x1 = set ? c1 : a1, x2 = set ? c2 : a2, x3 = set ? c3 : a3;
        uint4 w0 = { pk2bf(x0.x, x0.y), pk2bf(x0.z, x0.w), pk2bf(x1.x, x1.y), pk2bf(x1.z, x1.w) };
        uint4 w1 = { pk2bf(x2.x, x2.y), pk2bf(x2.z, x2.w), pk2bf(x3.x, x3.y), pk2bf(x3.z, x3.w) };
        *(uint4*)&Bs[buf][bsoff] = w0;
        *(uint4*)&Bs[buf][bsoff + 8] = w1;
    };
    auto compute = [&](int ring, int buf) {
        #pragma unroll
        for (int ks = 0; ks < 2; ++ks) {
            bf16x8 af[4], bfv[2];
            const int kc = ks * 4 + q;
            #pragma unroll
            for (int mi = 0; mi < 4; ++mi) {
                const int row = wm * 64 + mi * 16 + l16;
                af[mi] = *(const bf16x8*)&As[ring][row * 64 + (kc ^ (row & 7)) * 8];
            }
            #pragma unroll
            for (int ni = 0; ni < 2; ++ni) {
                const int col = wn * 32 + ni * 16 + l16;
                bfv[ni] = *(const bf16x8*)&Bs[buf][col * BPAD + ks * 32 + q * 8];
            }
            #pragma unroll
            for (int mi = 0; mi < 4; ++mi)
                #pragma unroll
                for (int ni = 0; ni < 2; ++ni)
                    acc[mi][ni] = __builtin_amdgcn_mfma_f32_16x16x32_bf16(af[mi], bfv[ni], acc[mi][ni], 0, 0, 0);
        }
    };

    // prologue: A(0)->r0, A(1)->r1; B(0)->set0 -> Bs[0]; B(1)->set1
    issueA(0, 0);
    issueA(1, BK);
    loadB0(0);
    __builtin_amdgcn_s_waitcnt(WAITCNT_VM0);
    writeB(0, 0);
    loadB1(BK);
    __syncthreads();

    int cur = 0;   // it2 % 3
    #pragma unroll 1
    for (int it2 = 0; it2 < KITERS; it2 += 2) {
        // ---- even it = it2: compute ring[cur], Bs[0]; B set0; A -> (cur+2)%3
        {
            const int it = it2;
            if (it + 2 < KITERS) { loadB0((it + 2) * BK); issueA((cur + 2) % 3, (it + 2) * BK); }
            compute(cur, 0);
            if (it + 2 < KITERS)      __builtin_amdgcn_s_waitcnt(WAITCNT_VM8);
            else if (it + 1 < KITERS) __builtin_amdgcn_s_waitcnt(WAITCNT_VM0);
            if (it + 1 < KITERS) {
                writeB(1, 1);   // B(it+1) from set1
                __builtin_amdgcn_s_waitcnt(WAITCNT_LGKM0);
                __builtin_amdgcn_s_barrier();
            }
        }
        // ---- odd it = it2+1: compute ring[(cur+1)%3], Bs[1]; B set1; A -> cur
        {
            const int it = it2 + 1;
            if (it + 2 < KITERS) { loadB1((it + 2) * BK); issueA(cur, (it + 2) * BK); }
            compute((cur + 1) % 3, 1);
            if (it + 2 < KITERS)      __builtin_amdgcn_s_waitcnt(WAITCNT_VM8);
            else if (it + 1 < KITERS) __builtin_amdgcn_s_waitcnt(WAITCNT_VM0);
            if (it + 1 < KITERS) {
                writeB(0, 0);   // B(it+1) from set0
                __builtin_amdgcn_s_waitcnt(WAITCNT_LGKM0);
                __builtin_amdgcn_s_barrier();
            }
        }
        cur = (cur + 2) % 3;
    }

    // epilogue: D row=(lane>>4)*4+reg, col=lane&15  [verified m89/m91]
    #pragma unroll
    for (int mi = 0; mi < 4; ++mi) {
        const int r0 = bm0 + wm * 64 + mi * 16 + q * 4;
        #pragma unroll
        for (int ni = 0; ni < 2; ++ni) {
            const int c0g = bn0 + wn * 32 + ni * 16 + l16;
            #pragma unroll
            for (int r = 0; r < 4; ++r)
                Cout[(size_t)(r0 + r) * C_SZ + c0g] = acc[mi][ni][r];
        }
    }

    // fused partial softmax over this block's 64 cols (per wave: 32 cols)
    #pragma unroll
    for (int mi = 0; mi < 4; ++mi) {
        #pragma unroll
        for (int r = 0; r < 4; ++r) {
            float mloc = fmaxf(acc[mi][0][r], acc[mi][1][r]);
            #pragma unroll
            for (int off = 1; off < 16; off <<= 1)
                mloc = fmaxf(mloc, __shfl_xor(mloc, off, 64));
            float sloc = __expf(acc[mi][0][r] - mloc) + __expf(acc[mi][1][r] - mloc);
            #pragma unroll
            for (int off = 1; off < 16; off <<= 1)
                sloc += __shfl_xor(sloc, off, 64);
            if (l16 == 0) {
                const int lrow = wm * 64 + mi * 16 + q * 4 + r;
                sm[lrow * 2 + wn] = mloc;
                ss2[lrow * 2 + wn] = sloc;
            }
        }
    }
    __syncthreads();
    if (tid < BM) {
        float m1 = sm[tid * 2], s1 = ss2[tid * 2];
        float m2 = sm[tid * 2 + 1], s2 = ss2[tid * 2 + 1];
        float nm = fmaxf(m1, m2);
        float s = s1 * __expf(m1 - nm) + s2 * __expf(m2 - nm);
        pmax[(bm0 + tid) * NTILE + slab] = nm;
        psum[(bm0 + tid) * NTILE + slab] = s;
    }
}

// ---------------- kernel 3: softmax merge + pair matching + hard-pair sums ----------------
__global__ __launch_bounds__(256) void pairs_kernel(
    const float* __restrict__ inputs, const int* __restrict__ targets,
    const int* __restrict__ ppairs, const int* __restrict__ npairs,
    const int* __restrict__ indexs, const int* __restrict__ cluster,
    const float* __restrict__ outputs, const float* __restrict__ norms,
    const float* __restrict__ pmax, const float* __restrict__ psum,
    float* __restrict__ bu_part, float* __restrict__ hp_part,
    float* __restrict__ hn_part, int* __restrict__ flag_part)
{
    const int i = blockIdx.x;
    const int tid = threadIdx.x;
    __shared__ int idxbuf[B_SZ];
    __shared__ int pj[P_SZ];
    __shared__ int nj[N_SZ];
    __shared__ float simp[P_SZ];
    __shared__ float simn[N_SZ];
    __shared__ float tnv[N_SZ];
    __shared__ float s_tp;
    __shared__ float rm[256], rs[256];

    idxbuf[tid] = indexs[tid];
    rm[tid] = pmax[i * NTILE + tid];
    rs[tid] = psum[i * NTILE + tid];
    __syncthreads();
    for (int s = 128; s > 0; s >>= 1) {
        if (tid < s) {
            float a = rm[tid], sa = rs[tid];
            float b = rm[tid + s], sb = rs[tid + s];
            float nn = fmaxf(a, b);
            rs[tid] = sa * __expf(a - nn) + sb * __expf(b - nn);
            rm[tid] = nn;
        }
        __syncthreads();
    }

    const float* row = outputs + (size_t)i * C_SZ;
    const float ni_norm = norms[i];

    if (tid == 0) {
        float logZ = rm[0] + logf(rs[0]);
        bu_part[i] = -(row[targets[i]] - logZ);
    }

    // pair matching (indexs is a permutation -> at most one match; argmax = first)
    if (tid < P_SZ) {
        int pp = ppairs[i * P_SZ + tid];
        int f = -1;
        if (pp >= 0) for (int j = 0; j < B_SZ; j++) if (idxbuf[j] == pp) { f = j; break; }
        pj[tid] = f;
    } else if (tid < P_SZ + N_SZ) {
        int t = tid - P_SZ;
        int np = npairs[i * N_SZ + t];
        int f = -1;
        if (np >= 0) for (int j = 0; j < B_SZ; j++) if (idxbuf[j] == np) { f = j; break; }
        nj[t] = f;
        int cid = cluster[np < 0 ? 0 : np];           // jnp.clip(npairs, 0)
        tnv[t] = row[cid] / ni_norm;                  // tsims[i, ncid] = outputs/norm
    }
    if (tid == P_SZ + N_SZ) s_tp = row[targets[i]] / ni_norm;
    __syncthreads();

    // in-batch sims (fp32, exact semantics incl. self-match ~1.0)
    const int lane = tid & 63, wv = tid >> 6;
    for (int qq = wv; qq < P_SZ + N_SZ; qq += 4) {
        int j = (qq < P_SZ) ? pj[qq] : nj[qq - P_SZ];
        float s = 0.f;
        if (j >= 0) {
            const float* xi = inputs + (size_t)i * F_SZ;
            const float* xj = inputs + (size_t)j * F_SZ;
            float d = 0.f;
            for (int k = lane; k < F_SZ; k += 64) d += xi[k] * xj[k];
            for (int off = 32; off > 0; off >>= 1) d += __shfl_down(d, off);
            s = d / (ni_norm * norms[j]);
        }
        if (lane == 0) { if (qq < P_SZ) simp[qq] = s; else simn[qq - P_SZ] = s; }
    }
    __syncthreads();

    if (tid == 0) {
        float psims[P_SZ + 1]; bool pmask[P_SZ + 1];
        for (int p = 0; p < P_SZ; p++) {
            int pp = ppairs[i * P_SZ + p];
            pmask[p] = (pj[p] >= 0) && (pp >= 0);
            psims[p] = simp[p];
        }
        psims[P_SZ] = s_tp; pmask[P_SZ] = (s_tp != 0.0f);

        float nsims[2 * N_SZ]; bool nmask[2 * N_SZ];
        for (int t = 0; t < N_SZ; t++) {
            int np = npairs[i * N_SZ + t];
            nmask[t] = (nj[t] >= 0) && (np >= 0);
            nsims[t] = simn[t];
            nsims[N_SZ + t] = tnv[t];
            nmask[N_SZ + t] = (np >= 0) && (tnv[t] != 0.0f);
        }
        bool anyp = false, anyn = false;
        float maxn = -INFINITY, minp = INFINITY;
        for (int t = 0; t < 2 * N_SZ; t++) if (nmask[t]) { anyn = true; maxn = fmaxf(maxn, nsims[t]); }
        for (int p = 0; p < P_SZ + 1; p++) if (pmask[p]) { anyp = true; minp = fminf(minp, psims[p]); }
        float p_thrd = (anyn ? maxn : -3.0f) + 0.1f;
        float n_thrd = (anyp ? minp : 3.0f) - 0.1f;
        float hps = 0.f, hns = 0.f; int fl = 0;
        for (int p = 0; p < P_SZ + 1; p++)
            if (pmask[p] && psims[p] < p_thrd) { fl |= 1; hps += expf(-2.0f * (psims[p] - 0.5f)); }
        for (int t = 0; t < 2 * N_SZ; t++)
            if (nmask[t] && nsims[t] > n_thrd && nsims[t] < 0.999999f) { fl |= 2; hns += expf(50.0f * (nsims[t] - 0.5f)); }
        hp_part[i] = hps; hn_part[i] = hns; flag_part[i] = fl;
    }
}

// ---------------- kernel 4: final scalar reduce ----------------
__global__ __launch_bounds__(256) void finalize_kernel(
    const float* __restrict__ bu_part, const float* __restrict__ hp_part,
    const float* __restrict__ hn_part, const int* __restrict__ flag_part,
    float* __restrict__ d_out)
{
    __shared__ float r1[256], r2[256], r3[256];
    __shared__ int rf[256];
    const int tid = threadIdx.x;
    r1[tid] = bu_part[tid]; r2[tid] = hp_part[tid]; r3[tid] = hn_part[tid]; rf[tid] = flag_part[tid];
    __syncthreads();
    for (int s = 128; s > 0; s >>= 1) {
        if (tid < s) { r1[tid] += r1[tid+s]; r2[tid] += r2[tid+s]; r3[tid] += r3[tid+s]; rf[tid] |= rf[tid+s]; }
        __syncthreads();
    }
    if (tid == 0) {
        float bu = r1[0] / (float)B_SZ;
        float hp_loss = (rf[0] & 1) ? 0.5f * log1pf(r2[0]) : 0.0f;
        float hn_loss = (rf[0] & 2) ? (1.0f / 50.0f) * log1pf(r3[0]) : 0.0f;
        d_out[0] = 1.0f * bu + 10.0f * (hp_loss + hn_loss);   // W_BU=1, W_H=10
    }
}

extern "C" void kernel_launch(void* const* d_in, const int* in_sizes, int n_in,
                              void* d_out, int out_size, void* d_ws, size_t ws_size,
                              hipStream_t stream) {
    const float* inputs  = (const float*)d_in[0];
    const int*   targets = (const int*)d_in[1];
    const int*   ppairs  = (const int*)d_in[2];
    const int*   npairs  = (const int*)d_in[3];
    const int*   indexs  = (const int*)d_in[4];
    const int*   cluster = (const int*)d_in[5];
    const float* V       = (const float*)d_in[6];
    float* out = (float*)d_out;           // [0] = loss, [1..] = outputs row-major [B][C]

    char* ws = (char*)d_ws;
    unsigned short* Abf = (unsigned short*)ws;                       // 1 MB
    float* norms   = (float*)(ws + (size_t)B_SZ * F_SZ * 2);
    float* bu_part = norms + B_SZ;
    float* hp_part = bu_part + B_SZ;
    float* hn_part = hp_part + B_SZ;
    int*   flag_part = (int*)(hn_part + B_SZ);
    float* pmax = (float*)(flag_part + B_SZ);                        // 256 KB
    float* psum = pmax + (size_t)B_SZ * NTILE;                       // 256 KB

    prep_kernel<<<B_SZ, 256, 0, stream>>>(inputs, Abf, norms);
    gemm_kernel<<<512, 256, 0, stream>>>(Abf, V, out + 1, pmax, psum);
    pairs_kernel<<<B_SZ, 256, 0, stream>>>(inputs, targets, ppairs, npairs, indexs,
                                           cluster, out + 1, norms, pmax, psum,
                                           bu_part, hp_part, hn_part, flag_part);
    finalize_kernel<<<1, 256, 0, stream>>>(bu_part, hp_part, hn_part, flag_part, out);
}